// Round 6
// baseline (4885.254 us; speedup 1.0000x reference)
//
#include <hip/hip_runtime.h>
#include <stdint.h>

typedef _Float16 f16;
typedef _Float16 f16x8 __attribute__((ext_vector_type(8)));
typedef _Float16 f16x2 __attribute__((ext_vector_type(2)));
typedef float f32x4 __attribute__((ext_vector_type(4)));

#define TT 512
#define BB 128
#define EE 200
#define H4 800

__device__ __forceinline__ float sigm_(float x) { return 1.f / (1.f + __expf(-x)); }
__device__ __forceinline__ float tanh_(float x) {
    x = fminf(15.f, fmaxf(-15.f, x));
    float e = __expf(2.f * x);
    return (e - 1.f) / (e + 1.f);
}

#if __has_builtin(__builtin_amdgcn_fdot2)
__device__ __forceinline__ float fdot2_(uint32_t w, uint32_t h, float acc) {
    return __builtin_amdgcn_fdot2(__builtin_bit_cast(f16x2, w), __builtin_bit_cast(f16x2, h), acc, false);
}
#else
__device__ __forceinline__ float fdot2_(uint32_t w, uint32_t h, float acc) {
    f16x2 a = __builtin_bit_cast(f16x2, w), b = __builtin_bit_cast(f16x2, h);
    return acc + (float)a[0] * (float)b[0] + (float)a[1] * (float)b[1];
}
#endif

// ---------------- weight conversion ----------------
__global__ void conv_w_kernel(const float* __restrict__ src, f16* __restrict__ dst,
                              int R, int K, int Rp, int Kp) {
    int idx = blockIdx.x * 256 + threadIdx.x;
    if (idx >= Rp * Kp) return;
    int r = idx / Kp, k = idx - r * Kp;
    dst[idx] = (r < R && k < K) ? (f16)src[r * K + k] : (f16)0.f;
}

// w1 (200,800) -> w1r (512,416): row j<200 = w1[j,0:400] (u), row 200+j = w1[j,400:800] (v)
__global__ void conv_w1r_kernel(const float* __restrict__ w1, f16* __restrict__ dst) {
    int idx = blockIdx.x * 256 + threadIdx.x;
    if (idx >= 512 * 416) return;
    int r = idx / 416, k = idx - r * 416;
    f16 v = (f16)0.f;
    if (r < 400 && k < 400) v = (f16)w1[(r % 200) * 800 + (r / 200) * 400 + k];
    dst[idx] = v;
}

// whh (800,200) f32 -> packed f16x2 row-major [j][kpair] (100 u32 per row)
__global__ void conv_whh_kernel(const float* __restrict__ s0, const float* __restrict__ s1,
                                const float* __restrict__ s2, const float* __restrict__ s3,
                                uint32_t* __restrict__ dst) {
    int z = blockIdx.y;
    int idx = blockIdx.x * 256 + threadIdx.x;
    if (idx >= 80000) return;
    const float* s = (z == 0) ? s0 : (z == 1) ? s1 : (z == 2) ? s2 : s3;
    int j = idx / 100, i = idx - j * 100;
    f16 lo = (f16)s[j * 200 + 2 * i], hi = (f16)s[j * 200 + 2 * i + 1];
    uint32_t u = ((uint32_t)__builtin_bit_cast(uint16_t, hi) << 16) |
                 (uint32_t)__builtin_bit_cast(uint16_t, lo);
    dst[z * 80000 + idx] = u;
}

__global__ void conv_bias_kernel(const float* bi0, const float* bh0, const float* bi1, const float* bh1,
                                 const float* bi2, const float* bh2, const float* bi3, const float* bh3,
                                 float* __restrict__ dst) {
    int z = blockIdx.y;
    int j = blockIdx.x * 256 + threadIdx.x;
    if (j >= 800) return;
    const float* bi = (z == 0) ? bi0 : (z == 1) ? bi1 : (z == 2) ? bi2 : bi3;
    const float* bh = (z == 0) ? bh0 : (z == 1) ? bh1 : (z == 2) ? bh2 : bh3;
    dst[z * 800 + j] = bi[j] + bh[j];
}

// ---------------- embedding gather -> padded f16 x (65536 x 224) ----------------
__global__ void xgather_kernel(const int* __restrict__ tokens, const float* __restrict__ emb,
                               f16* __restrict__ x) {
    int row = blockIdx.x;  // t*BB + b
    int e = threadIdx.x;
    if (e >= 224) return;
    int tok = tokens[row];
    f16 v = (f16)0.f;
    if (e < EE) v = (f16)emb[(size_t)tok * EE + e];
    x[(size_t)row * 224 + e] = v;
}

// ---------------- MFMA f16 GEMM: C[n,j] = sum_k A[arow+n,k]*B[j,k] + bias[j] ----------------
// A rows offset per z (chunked pre); reg-staged LDS (global_load_lds kept out until a green run).
__global__ __launch_bounds__(256, 2) void gemm_kernel(
    const f16* __restrict__ A, const f16* __restrict__ B0, const f16* __restrict__ B1,
    const float* __restrict__ bias0, const float* __restrict__ bias1,
    f16* __restrict__ C0, f16* __restrict__ C1,
    int N, int Kp, int nkt, int arow0, int arow1) {
    const f16* __restrict__ Bw = blockIdx.z ? B1 : B0;
    const float* __restrict__ bias = blockIdx.z ? bias1 : bias0;
    f16* __restrict__ C = blockIdx.z ? C1 : C0;
    const int arow = blockIdx.z ? arow1 : arow0;
    const int m0 = blockIdx.x * 128;
    const int n0 = blockIdx.y * 128;
    const int tid = threadIdx.x;

    __shared__ __align__(16) f16 sA[128 * 32];
    __shared__ __align__(16) f16 sB[128 * 32];

    const int r0 = tid >> 2, kc0 = (tid & 3) * 8;
    const int r1 = r0 + 64;
    const f16* ap0 = A + (size_t)(arow + m0 + r0) * Kp + kc0;
    const f16* ap1 = A + (size_t)(arow + m0 + r1) * Kp + kc0;
    const f16* bp0 = Bw + (size_t)(n0 + r0) * Kp + kc0;
    const f16* bp1 = Bw + (size_t)(n0 + r1) * Kp + kc0;

    const int wid = tid >> 6, lane = tid & 63;
    const int wm = (wid >> 1) * 64, wn = (wid & 1) * 64;
    const int fr = lane & 15, fk = (lane >> 4) * 8;

    f32x4 acc[4][4] = {};

    f16x8 a0 = *(const f16x8*)ap0;
    f16x8 a1 = *(const f16x8*)ap1;
    f16x8 b0 = *(const f16x8*)bp0;
    f16x8 b1 = *(const f16x8*)bp1;

    for (int kt = 0; kt < nkt; ++kt) {
        __syncthreads();
        *(f16x8*)&sA[tid * 8] = a0;
        *(f16x8*)&sA[(tid + 256) * 8] = a1;
        *(f16x8*)&sB[tid * 8] = b0;
        *(f16x8*)&sB[(tid + 256) * 8] = b1;
        __syncthreads();
        if (kt + 1 < nkt) {
            int ko = (kt + 1) * 32;
            a0 = *(const f16x8*)(ap0 + ko);
            a1 = *(const f16x8*)(ap1 + ko);
            b0 = *(const f16x8*)(bp0 + ko);
            b1 = *(const f16x8*)(bp1 + ko);
        }
        f16x8 af[4], bf[4];
#pragma unroll
        for (int i = 0; i < 4; ++i) af[i] = *(const f16x8*)&sA[(wm + i * 16 + fr) * 32 + fk];
#pragma unroll
        for (int i = 0; i < 4; ++i) bf[i] = *(const f16x8*)&sB[(wn + i * 16 + fr) * 32 + fk];
#pragma unroll
        for (int i = 0; i < 4; ++i)
#pragma unroll
            for (int j = 0; j < 4; ++j)
                acc[i][j] = __builtin_amdgcn_mfma_f32_16x16x32_f16(af[i], bf[j], acc[i][j], 0, 0, 0);
    }

    const int orow = (lane >> 4) * 4;  // C/D: col=lane&15, row=(lane>>4)*4+reg
#pragma unroll
    for (int i = 0; i < 4; ++i) {
#pragma unroll
        for (int j = 0; j < 4; ++j) {
            const int gcol = n0 + wn + j * 16 + fr;
            if (gcol < N) {
                const float bb = bias ? bias[gcol] : 0.f;
#pragma unroll
                for (int r = 0; r < 4; ++r) {
                    const int grow = m0 + wm + i * 16 + orow + r;
                    C[(size_t)grow * N + gcol] = (f16)(acc[i][j][r] + bb);
                }
            }
        }
    }
}

// ---------------- LSTM recurrence over one t-chunk; (h,c) state carried in ws ----------------
// block = (b, dir); 448 threads: 0..399 own gate-row pairs, 0..199 own cell lanes.
__global__ __launch_bounds__(448, 1) void rec_kernel(
    const f16* __restrict__ pre,  // [dir][S*BB*H4]
    const uint32_t* __restrict__ whh_f, const uint32_t* __restrict__ whh_b,
    f16* __restrict__ hout, int S, int tf0, int tb0,
    uint32_t* __restrict__ hstate, float* __restrict__ cstate, int first) {
    const int dir = blockIdx.x & 1;
    const int b = blockIdx.x >> 1;
    const f16* __restrict__ prez = pre + (size_t)dir * S * BB * H4;
    const uint32_t* __restrict__ whh = dir ? whh_b : whh_f;
    const int tid = threadIdx.x;

    __shared__ __align__(16) f16 hsh[200];
    __shared__ float gsh[800];

    uint4 w4a[25], w4b[25];  // rows 2*tid, 2*tid+1 of whh, f16x2-packed
    if (tid < 400) {
        const uint4* wr0 = (const uint4*)(whh + (size_t)(2 * tid) * 100);
        const uint4* wr1 = (const uint4*)(whh + (size_t)(2 * tid + 1) * 100);
#pragma unroll
        for (int i = 0; i < 25; ++i) w4a[i] = wr0[i];
#pragma unroll
        for (int i = 0; i < 25; ++i) w4b[i] = wr1[i];
    }
    if (tid < 100) ((uint32_t*)hsh)[tid] = first ? 0u : hstate[(dir * BB + b) * 100 + tid];
    float c = 0.f;
    if (!first && tid < 200) c = cstate[(dir * BB + b) * 200 + tid];
    __syncthreads();

    const int hoff = dir * 200;
    const bool istanh = (2 * tid >= 400 && 2 * tid < 600);
    float pv0 = 0.f, pv1 = 0.f;
    if (tid < 400) {
        int lt0 = dir ? (S - 1) : 0;
        f16x2 p = *(const f16x2*)&prez[((size_t)lt0 * BB + b) * H4 + 2 * tid];
        pv0 = (float)p[0]; pv1 = (float)p[1];
    }

    for (int step = 0; step < S; ++step) {
        const int lt = dir ? (S - 1 - step) : step;
        const int t = (dir ? tb0 : tf0) + lt;
        float acc0 = pv0, acc1 = pv1;
        if (tid < 400 && step + 1 < S) {  // prefetch next step's pre
            int ltn = dir ? (S - 2 - step) : (step + 1);
            f16x2 p = *(const f16x2*)&prez[((size_t)ltn * BB + b) * H4 + 2 * tid];
            pv0 = (float)p[0]; pv1 = (float)p[1];
        }
        if (tid < 400) {
            const uint4* hp = (const uint4*)hsh;
#pragma unroll
            for (int i = 0; i < 25; ++i) {
                uint4 q = hp[i];  // wave-uniform broadcast read
                acc0 = fdot2_(w4a[i].x, q.x, acc0);
                acc0 = fdot2_(w4a[i].y, q.y, acc0);
                acc0 = fdot2_(w4a[i].z, q.z, acc0);
                acc0 = fdot2_(w4a[i].w, q.w, acc0);
                acc1 = fdot2_(w4b[i].x, q.x, acc1);
                acc1 = fdot2_(w4b[i].y, q.y, acc1);
                acc1 = fdot2_(w4b[i].z, q.z, acc1);
                acc1 = fdot2_(w4b[i].w, q.w, acc1);
            }
            gsh[2 * tid] = istanh ? tanh_(acc0) : sigm_(acc0);
            gsh[2 * tid + 1] = istanh ? tanh_(acc1) : sigm_(acc1);
        }
        __syncthreads();
        if (tid < 200) {
            float ai = gsh[tid], af = gsh[200 + tid], ag = gsh[400 + tid], ao = gsh[600 + tid];
            c = af * c + ai * ag;
            float h = ao * tanh_(c);
            hsh[tid] = (f16)h;
            hout[((size_t)t * BB + b) * 416 + hoff + tid] = (f16)h;
        } else if (dir == 0 && tid >= 400 && tid < 416) {
            // zero K-pad cols [400,416) (ws poisoned; next GEMM reads Kp=416)
            hout[((size_t)t * BB + b) * 416 + 400 + (tid - 400)] = (f16)0.f;
        }
        __syncthreads();
    }
    // save carry state (hsh final after loop-ending barrier)
    if (tid < 100) hstate[(dir * BB + b) * 100 + tid] = ((const uint32_t*)hsh)[tid];
    if (tid < 200) cstate[(dir * BB + b) * 200 + tid] = c;
}

// ---------------- path gather + tanh + 4-logit + softmax: one wave per output row ----------------
__global__ void final_kernel(const int* __restrict__ paths, const f16* __restrict__ uv,
                             const float* __restrict__ b1, const float* __restrict__ w2,
                             const float* __restrict__ b2, float* __restrict__ out) {
    const int row = blockIdx.x * 4 + (threadIdx.x >> 6);  // b*256 + p, < 32768
    const int lane = threadIdx.x & 63;
    const int b = row >> 8;  // P = 256
    const int t0 = paths[row * 2], t1 = paths[row * 2 + 1];
    const f16* u = (t0 >= 0) ? (uv + ((size_t)t0 * BB + b) * 400) : nullptr;
    const f16* v = (t1 >= 0) ? (uv + ((size_t)t1 * BB + b) * 400 + 200) : nullptr;
    float l0 = 0.f, l1 = 0.f, l2 = 0.f, l3 = 0.f;
    for (int j = lane; j < 200; j += 64) {
        float s = b1[j];
        if (u) s += (float)u[j];
        if (v) s += (float)v[j];
        float hid = tanh_(s);
        l0 += hid * w2[j];
        l1 += hid * w2[200 + j];
        l2 += hid * w2[400 + j];
        l3 += hid * w2[600 + j];
    }
#pragma unroll
    for (int off = 32; off > 0; off >>= 1) {
        l0 += __shfl_down(l0, off);
        l1 += __shfl_down(l1, off);
        l2 += __shfl_down(l2, off);
        l3 += __shfl_down(l3, off);
    }
    if (lane == 0) {
        l0 += b2[0]; l1 += b2[1]; l2 += b2[2]; l3 += b2[3];
        float m = fmaxf(fmaxf(l0, l1), fmaxf(l2, l3));
        float e0 = __expf(l0 - m), e1 = __expf(l1 - m), e2 = __expf(l2 - m), e3 = __expf(l3 - m);
        float inv = 1.f / (e0 + e1 + e2 + e3);
        out[row * 4 + 0] = e0 * inv;
        out[row * 4 + 1] = e1 * inv;
        out[row * 4 + 2] = e2 * inv;
        out[row * 4 + 3] = e3 * inv;
    }
}

extern "C" void kernel_launch(void* const* d_in, const int* in_sizes, int n_in,
                              void* d_out, int out_size, void* d_ws, size_t ws_size,
                              hipStream_t stream) {
    (void)in_sizes; (void)n_in; (void)out_size;
    const int* tokens = (const int*)d_in[0];
    const int* paths = (const int*)d_in[1];
    const float* emb = (const float*)d_in[2];
    const float* wih0f = (const float*)d_in[3];
    const float* whh0f = (const float*)d_in[4];
    const float* bih0f = (const float*)d_in[5];
    const float* bhh0f = (const float*)d_in[6];
    const float* wih0b = (const float*)d_in[7];
    const float* whh0b = (const float*)d_in[8];
    const float* bih0b = (const float*)d_in[9];
    const float* bhh0b = (const float*)d_in[10];
    const float* wih1f = (const float*)d_in[11];
    const float* whh1f = (const float*)d_in[12];
    const float* bih1f = (const float*)d_in[13];
    const float* bhh1f = (const float*)d_in[14];
    const float* wih1b = (const float*)d_in[15];
    const float* whh1b = (const float*)d_in[16];
    const float* bih1b = (const float*)d_in[17];
    const float* bhh1b = (const float*)d_in[18];
    const float* w1 = (const float*)d_in[19];
    const float* b1 = (const float*)d_in[20];
    const float* w2 = (const float*)d_in[21];
    const float* b2 = (const float*)d_in[22];

    uint8_t* ws = (uint8_t*)d_ws;
    size_t off = 0;
    auto carve = [&](size_t bytes) {
        uint8_t* p = ws + off;
        off += (bytes + 255) & ~(size_t)255;
        return p;
    };
    f16* wih0f_h = (f16*)carve(896 * 224 * 2);
    f16* wih0b_h = (f16*)carve(896 * 224 * 2);
    f16* wih1f_h = (f16*)carve(896 * 416 * 2);
    f16* wih1b_h = (f16*)carve(896 * 416 * 2);
    f16* w1r_h = (f16*)carve(512 * 416 * 2);
    uint32_t* whhT = (uint32_t*)carve((size_t)4 * 80000 * 4);
    float* biasd = (float*)carve(4 * 800 * 4);
    uint32_t* hstate = (uint32_t*)carve((size_t)2 * BB * 100 * 4);
    float* cstate = (float*)carve((size_t)2 * BB * 200 * 4);
    f16* xh = (f16*)carve((size_t)65536 * 224 * 2);
    f16* h0h = (f16*)carve((size_t)65536 * 416 * 2);
    f16* h1h = (f16*)carve((size_t)65536 * 416 * 2);
    // pre chunk: largest S (steps/chunk) whose both-direction buffer fits ws_size
    int S = TT;
    while (S > 32 && off + ((size_t)2 * S * BB * H4 * 2 + 256) > ws_size) S >>= 1;
    f16* pre = (f16*)carve((size_t)2 * S * BB * H4 * 2);
    f16* pre_b = pre + (size_t)S * BB * H4;
    f16* uvh = h0h;  // uv (65536x400 f16 = 52.4 MB) aliases h0h (dead after layer-1 GEMM)
    const int nch = TT / S;

    conv_w_kernel<<<784, 256, 0, stream>>>(wih0f, wih0f_h, 800, 200, 896, 224);
    conv_w_kernel<<<784, 256, 0, stream>>>(wih0b, wih0b_h, 800, 200, 896, 224);
    conv_w_kernel<<<1456, 256, 0, stream>>>(wih1f, wih1f_h, 800, 400, 896, 416);
    conv_w_kernel<<<1456, 256, 0, stream>>>(wih1b, wih1b_h, 800, 400, 896, 416);
    conv_w1r_kernel<<<832, 256, 0, stream>>>(w1, w1r_h);
    conv_whh_kernel<<<dim3(313, 4), 256, 0, stream>>>(whh0f, whh0b, whh1f, whh1b, whhT);
    conv_bias_kernel<<<dim3(4, 4), 256, 0, stream>>>(bih0f, bhh0f, bih0b, bhh0b,
                                                     bih1f, bhh1f, bih1b, bhh1b, biasd);
    xgather_kernel<<<65536, 256, 0, stream>>>(tokens, emb, xh);

    // layer 0
    for (int c = 0; c < nch; ++c) {
        const int tf0 = c * S, tb0 = TT - (c + 1) * S;
        gemm_kernel<<<dim3(S, 7, 2), 256, 0, stream>>>(xh, wih0f_h, wih0b_h, biasd, biasd + 800,
                                                       pre, pre_b, 800, 224, 7, tf0 * BB, tb0 * BB);
        rec_kernel<<<256, 448, 0, stream>>>(pre, whhT, whhT + 80000, h0h, S, tf0, tb0,
                                            hstate, cstate, c == 0);
    }
    // layer 1
    for (int c = 0; c < nch; ++c) {
        const int tf0 = c * S, tb0 = TT - (c + 1) * S;
        gemm_kernel<<<dim3(S, 7, 2), 256, 0, stream>>>(h0h, wih1f_h, wih1b_h, biasd + 1600, biasd + 2400,
                                                       pre, pre_b, 800, 416, 13, tf0 * BB, tb0 * BB);
        rec_kernel<<<256, 448, 0, stream>>>(pre, whhT + 160000, whhT + 240000, h1h, S, tf0, tb0,
                                            hstate, cstate, c == 0);
    }
    // MLP precompute uv then fused gather+softmax
    gemm_kernel<<<dim3(512, 4, 1), 256, 0, stream>>>(h1h, w1r_h, nullptr, nullptr, nullptr,
                                                     uvh, nullptr, 400, 416, 13, 0, 0);
    final_kernel<<<8192, 256, 0, stream>>>(paths, uvh, b1, w2, b2, (float*)d_out);
}

// Round 7
// 4768.472 us; speedup vs baseline: 1.0245x; 1.0245x over previous
//
#include <hip/hip_runtime.h>
#include <stdint.h>

typedef _Float16 f16;
typedef _Float16 f16x8 __attribute__((ext_vector_type(8)));
typedef _Float16 f16x2 __attribute__((ext_vector_type(2)));
typedef float f32x4 __attribute__((ext_vector_type(4)));

#define TT 512
#define BB 128
#define EE 200
#define H4 800

__device__ __forceinline__ float sigm_(float x) { return 1.f / (1.f + __expf(-x)); }
__device__ __forceinline__ float tanh_(float x) {
    x = fminf(15.f, fmaxf(-15.f, x));
    float e = __expf(2.f * x);
    return (e - 1.f) / (e + 1.f);
}

#if __has_builtin(__builtin_amdgcn_fdot2)
__device__ __forceinline__ float fdot2_(uint32_t w, uint32_t h, float acc) {
    return __builtin_amdgcn_fdot2(__builtin_bit_cast(f16x2, w), __builtin_bit_cast(f16x2, h), acc, false);
}
#else
__device__ __forceinline__ float fdot2_(uint32_t w, uint32_t h, float acc) {
    f16x2 a = __builtin_bit_cast(f16x2, w), b = __builtin_bit_cast(f16x2, h);
    return acc + (float)a[0] * (float)b[0] + (float)a[1] * (float)b[1];
}
#endif

// ---------------- weight conversion ----------------
__global__ void conv_w_kernel(const float* __restrict__ src, f16* __restrict__ dst,
                              int R, int K, int Rp, int Kp) {
    int idx = blockIdx.x * 256 + threadIdx.x;
    if (idx >= Rp * Kp) return;
    int r = idx / Kp, k = idx - r * Kp;
    dst[idx] = (r < R && k < K) ? (f16)src[r * K + k] : (f16)0.f;
}

// w1 (200,800) -> w1r (512,416): row j<200 = w1[j,0:400] (u), row 200+j = w1[j,400:800] (v)
__global__ void conv_w1r_kernel(const float* __restrict__ w1, f16* __restrict__ dst) {
    int idx = blockIdx.x * 256 + threadIdx.x;
    if (idx >= 512 * 416) return;
    int r = idx / 416, k = idx - r * 416;
    f16 v = (f16)0.f;
    if (r < 400 && k < 400) v = (f16)w1[(r % 200) * 800 + (r / 200) * 400 + k];
    dst[idx] = v;
}

// whh (800,200) f32 -> packed f16x2 row-major [j][kpair] (100 u32 per row)
__global__ void conv_whh_kernel(const float* __restrict__ s0, const float* __restrict__ s1,
                                const float* __restrict__ s2, const float* __restrict__ s3,
                                uint32_t* __restrict__ dst) {
    int z = blockIdx.y;
    int idx = blockIdx.x * 256 + threadIdx.x;
    if (idx >= 80000) return;
    const float* s = (z == 0) ? s0 : (z == 1) ? s1 : (z == 2) ? s2 : s3;
    int j = idx / 100, i = idx - j * 100;
    f16 lo = (f16)s[j * 200 + 2 * i], hi = (f16)s[j * 200 + 2 * i + 1];
    uint32_t u = ((uint32_t)__builtin_bit_cast(uint16_t, hi) << 16) |
                 (uint32_t)__builtin_bit_cast(uint16_t, lo);
    dst[z * 80000 + idx] = u;
}

__global__ void conv_bias_kernel(const float* bi0, const float* bh0, const float* bi1, const float* bh1,
                                 const float* bi2, const float* bh2, const float* bi3, const float* bh3,
                                 float* __restrict__ dst) {
    int z = blockIdx.y;
    int j = blockIdx.x * 256 + threadIdx.x;
    if (j >= 800) return;
    const float* bi = (z == 0) ? bi0 : (z == 1) ? bi1 : (z == 2) ? bi2 : bi3;
    const float* bh = (z == 0) ? bh0 : (z == 1) ? bh1 : (z == 2) ? bh2 : bh3;
    dst[z * 800 + j] = bi[j] + bh[j];
}

// ---------------- embedding gather -> padded f16 x (65536 x 224) ----------------
__global__ void xgather_kernel(const int* __restrict__ tokens, const float* __restrict__ emb,
                               f16* __restrict__ x) {
    int row = blockIdx.x;  // t*BB + b
    int e = threadIdx.x;
    if (e >= 224) return;
    int tok = tokens[row];
    f16 v = (f16)0.f;
    if (e < EE) v = (f16)emb[(size_t)tok * EE + e];
    x[(size_t)row * 224 + e] = v;
}

// ---------------- MFMA f16 GEMM: C[n,j] = sum_k A[arow+n,k]*B[j,k] + bias[j] ----------------
__global__ __launch_bounds__(256, 2) void gemm_kernel(
    const f16* __restrict__ A, const f16* __restrict__ B0, const f16* __restrict__ B1,
    const float* __restrict__ bias0, const float* __restrict__ bias1,
    f16* __restrict__ C0, f16* __restrict__ C1,
    int N, int Kp, int nkt, int arow0, int arow1) {
    const f16* __restrict__ Bw = blockIdx.z ? B1 : B0;
    const float* __restrict__ bias = blockIdx.z ? bias1 : bias0;
    f16* __restrict__ C = blockIdx.z ? C1 : C0;
    const int arow = blockIdx.z ? arow1 : arow0;
    const int m0 = blockIdx.x * 128;
    const int n0 = blockIdx.y * 128;
    const int tid = threadIdx.x;

    __shared__ __align__(16) f16 sA[128 * 32];
    __shared__ __align__(16) f16 sB[128 * 32];

    const int r0 = tid >> 2, kc0 = (tid & 3) * 8;
    const int r1 = r0 + 64;
    const f16* ap0 = A + (size_t)(arow + m0 + r0) * Kp + kc0;
    const f16* ap1 = A + (size_t)(arow + m0 + r1) * Kp + kc0;
    const f16* bp0 = Bw + (size_t)(n0 + r0) * Kp + kc0;
    const f16* bp1 = Bw + (size_t)(n0 + r1) * Kp + kc0;

    const int wid = tid >> 6, lane = tid & 63;
    const int wm = (wid >> 1) * 64, wn = (wid & 1) * 64;
    const int fr = lane & 15, fk = (lane >> 4) * 8;

    f32x4 acc[4][4] = {};

    f16x8 a0 = *(const f16x8*)ap0;
    f16x8 a1 = *(const f16x8*)ap1;
    f16x8 b0 = *(const f16x8*)bp0;
    f16x8 b1 = *(const f16x8*)bp1;

    for (int kt = 0; kt < nkt; ++kt) {
        __syncthreads();
        *(f16x8*)&sA[tid * 8] = a0;
        *(f16x8*)&sA[(tid + 256) * 8] = a1;
        *(f16x8*)&sB[tid * 8] = b0;
        *(f16x8*)&sB[(tid + 256) * 8] = b1;
        __syncthreads();
        if (kt + 1 < nkt) {
            int ko = (kt + 1) * 32;
            a0 = *(const f16x8*)(ap0 + ko);
            a1 = *(const f16x8*)(ap1 + ko);
            b0 = *(const f16x8*)(bp0 + ko);
            b1 = *(const f16x8*)(bp1 + ko);
        }
        f16x8 af[4], bf[4];
#pragma unroll
        for (int i = 0; i < 4; ++i) af[i] = *(const f16x8*)&sA[(wm + i * 16 + fr) * 32 + fk];
#pragma unroll
        for (int i = 0; i < 4; ++i) bf[i] = *(const f16x8*)&sB[(wn + i * 16 + fr) * 32 + fk];
#pragma unroll
        for (int i = 0; i < 4; ++i)
#pragma unroll
            for (int j = 0; j < 4; ++j)
                acc[i][j] = __builtin_amdgcn_mfma_f32_16x16x32_f16(af[i], bf[j], acc[i][j], 0, 0, 0);
    }

    const int orow = (lane >> 4) * 4;  // C/D: col=lane&15, row=(lane>>4)*4+reg
#pragma unroll
    for (int i = 0; i < 4; ++i) {
#pragma unroll
        for (int j = 0; j < 4; ++j) {
            const int gcol = n0 + wn + j * 16 + fr;
            if (gcol < N) {
                const float bb = bias ? bias[gcol] : 0.f;
#pragma unroll
                for (int r = 0; r < 4; ++r) {
                    const int grow = m0 + wm + i * 16 + orow + r;
                    C[(size_t)grow * N + gcol] = (f16)(acc[i][j][r] + bb);
                }
            }
        }
    }
}

// ---------------- LSTM recurrence over one t-chunk; (h,c) state carried in ws ----------------
// block = (b, dir); 448 threads: 0..399 own gate-row pairs, 0..199 own cell lanes.
// R7: whh weights in 50 NAMED uint4 registers (R6 profile: VGPR_Count=128 -> arrays had
// spilled to scratch; named scalars + launch_bounds(448,2) force register residency).
#define REP25(M) M(0) M(1) M(2) M(3) M(4) M(5) M(6) M(7) M(8) M(9) M(10) M(11) M(12) \
                 M(13) M(14) M(15) M(16) M(17) M(18) M(19) M(20) M(21) M(22) M(23) M(24)

__global__ __launch_bounds__(448, 2) void rec_kernel(
    const f16* __restrict__ pre,  // [dir][S*BB*H4]
    const uint32_t* __restrict__ whh_f, const uint32_t* __restrict__ whh_b,
    f16* __restrict__ hout, int S, int tf0, int tb0,
    uint32_t* __restrict__ hstate, float* __restrict__ cstate, int first) {
    const int dir = blockIdx.x & 1;
    const int b = blockIdx.x >> 1;
    const f16* __restrict__ prez = pre + (size_t)dir * S * BB * H4;
    const uint32_t* __restrict__ whh = dir ? whh_b : whh_f;
    const int tid = threadIdx.x;

    __shared__ __align__(16) f16 hsh[200];
    __shared__ float gsh[800];

    // non-divergent weight load: threads >=400 load row 0 (values unused)
    const int wrow = (tid < 400) ? (2 * tid) : 0;
    const uint4* wr0 = (const uint4*)(whh + (size_t)wrow * 100);
    const uint4* wr1 = (const uint4*)(whh + (size_t)(wrow + 1) * 100);
#define WLOAD(n) uint4 wa##n = wr0[n]; uint4 wb##n = wr1[n];
    REP25(WLOAD)
#undef WLOAD

    if (tid < 100) ((uint32_t*)hsh)[tid] = first ? 0u : hstate[(dir * BB + b) * 100 + tid];
    float c = 0.f;
    if (!first && tid < 200) c = cstate[(dir * BB + b) * 200 + tid];
    __syncthreads();

    const int hoff = dir * 200;
    const bool istanh = (2 * tid >= 400 && 2 * tid < 600);
    float pv0 = 0.f, pv1 = 0.f;
    if (tid < 400) {
        int lt0 = dir ? (S - 1) : 0;
        f16x2 p = *(const f16x2*)&prez[((size_t)lt0 * BB + b) * H4 + 2 * tid];
        pv0 = (float)p[0]; pv1 = (float)p[1];
    }

    for (int step = 0; step < S; ++step) {
        const int lt = dir ? (S - 1 - step) : step;
        const int t = (dir ? tb0 : tf0) + lt;
        float acc0 = pv0, acc1 = pv1;
        if (tid < 400 && step + 1 < S) {  // prefetch next step's pre
            int ltn = dir ? (S - 2 - step) : (step + 1);
            f16x2 p = *(const f16x2*)&prez[((size_t)ltn * BB + b) * H4 + 2 * tid];
            pv0 = (float)p[0]; pv1 = (float)p[1];
        }
        if (tid < 400) {
            const uint4* hp = (const uint4*)hsh;
#define WDOT(n) { uint4 q = hp[n]; \
            acc0 = fdot2_(wa##n.x, q.x, acc0); \
            acc0 = fdot2_(wa##n.y, q.y, acc0); \
            acc0 = fdot2_(wa##n.z, q.z, acc0); \
            acc0 = fdot2_(wa##n.w, q.w, acc0); \
            acc1 = fdot2_(wb##n.x, q.x, acc1); \
            acc1 = fdot2_(wb##n.y, q.y, acc1); \
            acc1 = fdot2_(wb##n.z, q.z, acc1); \
            acc1 = fdot2_(wb##n.w, q.w, acc1); }
            REP25(WDOT)
#undef WDOT
            gsh[2 * tid] = istanh ? tanh_(acc0) : sigm_(acc0);
            gsh[2 * tid + 1] = istanh ? tanh_(acc1) : sigm_(acc1);
        }
        __syncthreads();
        if (tid < 200) {
            float ai = gsh[tid], af = gsh[200 + tid], ag = gsh[400 + tid], ao = gsh[600 + tid];
            c = af * c + ai * ag;
            float h = ao * tanh_(c);
            hsh[tid] = (f16)h;
            hout[((size_t)t * BB + b) * 416 + hoff + tid] = (f16)h;
        } else if (dir == 0 && tid >= 400 && tid < 416) {
            // zero K-pad cols [400,416) (ws poisoned; next GEMM reads Kp=416)
            hout[((size_t)t * BB + b) * 416 + 400 + (tid - 400)] = (f16)0.f;
        }
        __syncthreads();
    }
    // save carry state (hsh final after loop-ending barrier)
    if (tid < 100) hstate[(dir * BB + b) * 100 + tid] = ((const uint32_t*)hsh)[tid];
    if (tid < 200) cstate[(dir * BB + b) * 200 + tid] = c;
}

// ---------------- path gather + tanh + 4-logit + softmax: one wave per output row ----------------
__global__ void final_kernel(const int* __restrict__ paths, const f16* __restrict__ uv,
                             const float* __restrict__ b1, const float* __restrict__ w2,
                             const float* __restrict__ b2, float* __restrict__ out) {
    const int row = blockIdx.x * 4 + (threadIdx.x >> 6);  // b*256 + p, < 32768
    const int lane = threadIdx.x & 63;
    const int b = row >> 8;  // P = 256
    const int t0 = paths[row * 2], t1 = paths[row * 2 + 1];
    const f16* u = (t0 >= 0) ? (uv + ((size_t)t0 * BB + b) * 400) : nullptr;
    const f16* v = (t1 >= 0) ? (uv + ((size_t)t1 * BB + b) * 400 + 200) : nullptr;
    float l0 = 0.f, l1 = 0.f, l2 = 0.f, l3 = 0.f;
    for (int j = lane; j < 200; j += 64) {
        float s = b1[j];
        if (u) s += (float)u[j];
        if (v) s += (float)v[j];
        float hid = tanh_(s);
        l0 += hid * w2[j];
        l1 += hid * w2[200 + j];
        l2 += hid * w2[400 + j];
        l3 += hid * w2[600 + j];
    }
#pragma unroll
    for (int off = 32; off > 0; off >>= 1) {
        l0 += __shfl_down(l0, off);
        l1 += __shfl_down(l1, off);
        l2 += __shfl_down(l2, off);
        l3 += __shfl_down(l3, off);
    }
    if (lane == 0) {
        l0 += b2[0]; l1 += b2[1]; l2 += b2[2]; l3 += b2[3];
        float m = fmaxf(fmaxf(l0, l1), fmaxf(l2, l3));
        float e0 = __expf(l0 - m), e1 = __expf(l1 - m), e2 = __expf(l2 - m), e3 = __expf(l3 - m);
        float inv = 1.f / (e0 + e1 + e2 + e3);
        out[row * 4 + 0] = e0 * inv;
        out[row * 4 + 1] = e1 * inv;
        out[row * 4 + 2] = e2 * inv;
        out[row * 4 + 3] = e3 * inv;
    }
}

extern "C" void kernel_launch(void* const* d_in, const int* in_sizes, int n_in,
                              void* d_out, int out_size, void* d_ws, size_t ws_size,
                              hipStream_t stream) {
    (void)in_sizes; (void)n_in; (void)out_size;
    const int* tokens = (const int*)d_in[0];
    const int* paths = (const int*)d_in[1];
    const float* emb = (const float*)d_in[2];
    const float* wih0f = (const float*)d_in[3];
    const float* whh0f = (const float*)d_in[4];
    const float* bih0f = (const float*)d_in[5];
    const float* bhh0f = (const float*)d_in[6];
    const float* wih0b = (const float*)d_in[7];
    const float* whh0b = (const float*)d_in[8];
    const float* bih0b = (const float*)d_in[9];
    const float* bhh0b = (const float*)d_in[10];
    const float* wih1f = (const float*)d_in[11];
    const float* whh1f = (const float*)d_in[12];
    const float* bih1f = (const float*)d_in[13];
    const float* bhh1f = (const float*)d_in[14];
    const float* wih1b = (const float*)d_in[15];
    const float* whh1b = (const float*)d_in[16];
    const float* bih1b = (const float*)d_in[17];
    const float* bhh1b = (const float*)d_in[18];
    const float* w1 = (const float*)d_in[19];
    const float* b1 = (const float*)d_in[20];
    const float* w2 = (const float*)d_in[21];
    const float* b2 = (const float*)d_in[22];

    uint8_t* ws = (uint8_t*)d_ws;
    size_t off = 0;
    auto carve = [&](size_t bytes) {
        uint8_t* p = ws + off;
        off += (bytes + 255) & ~(size_t)255;
        return p;
    };
    f16* wih0f_h = (f16*)carve(896 * 224 * 2);
    f16* wih0b_h = (f16*)carve(896 * 224 * 2);
    f16* wih1f_h = (f16*)carve(896 * 416 * 2);
    f16* wih1b_h = (f16*)carve(896 * 416 * 2);
    f16* w1r_h = (f16*)carve(512 * 416 * 2);
    uint32_t* whhT = (uint32_t*)carve((size_t)4 * 80000 * 4);
    float* biasd = (float*)carve(4 * 800 * 4);
    uint32_t* hstate = (uint32_t*)carve((size_t)2 * BB * 100 * 4);
    float* cstate = (float*)carve((size_t)2 * BB * 200 * 4);
    f16* xh = (f16*)carve((size_t)65536 * 224 * 2);
    f16* h0h = (f16*)carve((size_t)65536 * 416 * 2);
    f16* h1h = (f16*)carve((size_t)65536 * 416 * 2);
    // pre chunk: largest S (steps/chunk) whose both-direction buffer fits ws_size
    int S = TT;
    while (S > 32 && off + ((size_t)2 * S * BB * H4 * 2 + 256) > ws_size) S >>= 1;
    f16* pre = (f16*)carve((size_t)2 * S * BB * H4 * 2);
    f16* pre_b = pre + (size_t)S * BB * H4;
    f16* uvh = h0h;  // uv (65536x400 f16 = 52.4 MB) aliases h0h (dead after layer-1 GEMM)
    const int nch = TT / S;

    conv_w_kernel<<<784, 256, 0, stream>>>(wih0f, wih0f_h, 800, 200, 896, 224);
    conv_w_kernel<<<784, 256, 0, stream>>>(wih0b, wih0b_h, 800, 200, 896, 224);
    conv_w_kernel<<<1456, 256, 0, stream>>>(wih1f, wih1f_h, 800, 400, 896, 416);
    conv_w_kernel<<<1456, 256, 0, stream>>>(wih1b, wih1b_h, 800, 400, 896, 416);
    conv_w1r_kernel<<<832, 256, 0, stream>>>(w1, w1r_h);
    conv_whh_kernel<<<dim3(313, 4), 256, 0, stream>>>(whh0f, whh0b, whh1f, whh1b, whhT);
    conv_bias_kernel<<<dim3(4, 4), 256, 0, stream>>>(bih0f, bhh0f, bih0b, bhh0b,
                                                     bih1f, bhh1f, bih1b, bhh1b, biasd);
    xgather_kernel<<<65536, 256, 0, stream>>>(tokens, emb, xh);

    // layer 0
    for (int c = 0; c < nch; ++c) {
        const int tf0 = c * S, tb0 = TT - (c + 1) * S;
        gemm_kernel<<<dim3(S, 7, 2), 256, 0, stream>>>(xh, wih0f_h, wih0b_h, biasd, biasd + 800,
                                                       pre, pre_b, 800, 224, 7, tf0 * BB, tb0 * BB);
        rec_kernel<<<256, 448, 0, stream>>>(pre, whhT, whhT + 80000, h0h, S, tf0, tb0,
                                            hstate, cstate, c == 0);
    }
    // layer 1
    for (int c = 0; c < nch; ++c) {
        const int tf0 = c * S, tb0 = TT - (c + 1) * S;
        gemm_kernel<<<dim3(S, 7, 2), 256, 0, stream>>>(h0h, wih1f_h, wih1b_h, biasd + 1600, biasd + 2400,
                                                       pre, pre_b, 800, 416, 13, tf0 * BB, tb0 * BB);
        rec_kernel<<<256, 448, 0, stream>>>(pre, whhT + 160000, whhT + 240000, h1h, S, tf0, tb0,
                                            hstate, cstate, c == 0);
    }
    // MLP precompute uv then fused gather+softmax
    gemm_kernel<<<dim3(512, 4, 1), 256, 0, stream>>>(h1h, w1r_h, nullptr, nullptr, nullptr,
                                                     uvh, nullptr, 400, 416, 13, 0, 0);
    final_kernel<<<8192, 256, 0, stream>>>(paths, uvh, b1, w2, b2, (float*)d_out);
}

// Round 9
// 2075.502 us; speedup vs baseline: 2.3538x; 2.2975x over previous
//
#include <hip/hip_runtime.h>
#include <stdint.h>

typedef _Float16 f16;
typedef _Float16 f16x8 __attribute__((ext_vector_type(8)));
typedef _Float16 f16x2 __attribute__((ext_vector_type(2)));
typedef float f32x4 __attribute__((ext_vector_type(4)));

#define TT 512
#define BB 128
#define EE 200
#define H4 800

__device__ __forceinline__ float sigm_(float x) { return 1.f / (1.f + __expf(-x)); }
__device__ __forceinline__ float tanh_(float x) {
    x = fminf(15.f, fmaxf(-15.f, x));
    float e = __expf(2.f * x);
    return (e - 1.f) / (e + 1.f);
}

#if __has_builtin(__builtin_amdgcn_fdot2)
__device__ __forceinline__ float fdot2_(uint32_t w, uint32_t h, float acc) {
    return __builtin_amdgcn_fdot2(__builtin_bit_cast(f16x2, w), __builtin_bit_cast(f16x2, h), acc, false);
}
#else
__device__ __forceinline__ float fdot2_(uint32_t w, uint32_t h, float acc) {
    f16x2 a = __builtin_bit_cast(f16x2, w), b = __builtin_bit_cast(f16x2, h);
    return acc + (float)a[0] * (float)b[0] + (float)a[1] * (float)b[1];
}
#endif

// ---------------- weight conversion ----------------
__global__ void conv_w_kernel(const float* __restrict__ src, f16* __restrict__ dst,
                              int R, int K, int Rp, int Kp) {
    int idx = blockIdx.x * 256 + threadIdx.x;
    if (idx >= Rp * Kp) return;
    int r = idx / Kp, k = idx - r * Kp;
    dst[idx] = (r < R && k < K) ? (f16)src[r * K + k] : (f16)0.f;
}

// w1 (200,800) -> w1r (512,416): row j<200 = w1[j,0:400] (u), row 200+j = w1[j,400:800] (v)
__global__ void conv_w1r_kernel(const float* __restrict__ w1, f16* __restrict__ dst) {
    int idx = blockIdx.x * 256 + threadIdx.x;
    if (idx >= 512 * 416) return;
    int r = idx / 416, k = idx - r * 416;
    f16 v = (f16)0.f;
    if (r < 400 && k < 400) v = (f16)w1[(r % 200) * 800 + (r / 200) * 400 + k];
    dst[idx] = v;
}

// whh (800,200) f32 -> packed f16x2 row-major [j][kpair] (100 u32 per row)
__global__ void conv_whh_kernel(const float* __restrict__ s0, const float* __restrict__ s1,
                                const float* __restrict__ s2, const float* __restrict__ s3,
                                uint32_t* __restrict__ dst) {
    int z = blockIdx.y;
    int idx = blockIdx.x * 256 + threadIdx.x;
    if (idx >= 80000) return;
    const float* s = (z == 0) ? s0 : (z == 1) ? s1 : (z == 2) ? s2 : s3;
    int j = idx / 100, i = idx - j * 100;
    f16 lo = (f16)s[j * 200 + 2 * i], hi = (f16)s[j * 200 + 2 * i + 1];
    uint32_t u = ((uint32_t)__builtin_bit_cast(uint16_t, hi) << 16) |
                 (uint32_t)__builtin_bit_cast(uint16_t, lo);
    dst[z * 80000 + idx] = u;
}

__global__ void conv_bias_kernel(const float* bi0, const float* bh0, const float* bi1, const float* bh1,
                                 const float* bi2, const float* bh2, const float* bi3, const float* bh3,
                                 float* __restrict__ dst) {
    int z = blockIdx.y;
    int j = blockIdx.x * 256 + threadIdx.x;
    if (j >= 800) return;
    const float* bi = (z == 0) ? bi0 : (z == 1) ? bi1 : (z == 2) ? bi2 : bi3;
    const float* bh = (z == 0) ? bh0 : (z == 1) ? bh1 : (z == 2) ? bh2 : bh3;
    dst[z * 800 + j] = bi[j] + bh[j];
}

// ---------------- embedding gather -> padded f16 x (65536 x 224) ----------------
__global__ void xgather_kernel(const int* __restrict__ tokens, const float* __restrict__ emb,
                               f16* __restrict__ x) {
    int row = blockIdx.x;  // t*BB + b
    int e = threadIdx.x;
    if (e >= 224) return;
    int tok = tokens[row];
    f16 v = (f16)0.f;
    if (e < EE) v = (f16)emb[(size_t)tok * EE + e];
    x[(size_t)row * 224 + e] = v;
}

// ---------------- MFMA f16 GEMM: C[n,j] = sum_k A[arow+n,k]*B[j,k] + bias[j] ----------------
__global__ __launch_bounds__(256, 2) void gemm_kernel(
    const f16* __restrict__ A, const f16* __restrict__ B0, const f16* __restrict__ B1,
    const float* __restrict__ bias0, const float* __restrict__ bias1,
    f16* __restrict__ C0, f16* __restrict__ C1,
    int N, int Kp, int nkt, int arow0, int arow1) {
    const f16* __restrict__ Bw = blockIdx.z ? B1 : B0;
    const float* __restrict__ bias = blockIdx.z ? bias1 : bias0;
    f16* __restrict__ C = blockIdx.z ? C1 : C0;
    const int arow = blockIdx.z ? arow1 : arow0;
    const int m0 = blockIdx.x * 128;
    const int n0 = blockIdx.y * 128;
    const int tid = threadIdx.x;

    __shared__ __align__(16) f16 sA[128 * 32];
    __shared__ __align__(16) f16 sB[128 * 32];

    const int r0 = tid >> 2, kc0 = (tid & 3) * 8;
    const int r1 = r0 + 64;
    const f16* ap0 = A + (size_t)(arow + m0 + r0) * Kp + kc0;
    const f16* ap1 = A + (size_t)(arow + m0 + r1) * Kp + kc0;
    const f16* bp0 = Bw + (size_t)(n0 + r0) * Kp + kc0;
    const f16* bp1 = Bw + (size_t)(n0 + r1) * Kp + kc0;

    const int wid = tid >> 6, lane = tid & 63;
    const int wm = (wid >> 1) * 64, wn = (wid & 1) * 64;
    const int fr = lane & 15, fk = (lane >> 4) * 8;

    f32x4 acc[4][4] = {};

    f16x8 a0 = *(const f16x8*)ap0;
    f16x8 a1 = *(const f16x8*)ap1;
    f16x8 b0 = *(const f16x8*)bp0;
    f16x8 b1 = *(const f16x8*)bp1;

    for (int kt = 0; kt < nkt; ++kt) {
        __syncthreads();
        *(f16x8*)&sA[tid * 8] = a0;
        *(f16x8*)&sA[(tid + 256) * 8] = a1;
        *(f16x8*)&sB[tid * 8] = b0;
        *(f16x8*)&sB[(tid + 256) * 8] = b1;
        __syncthreads();
        if (kt + 1 < nkt) {
            int ko = (kt + 1) * 32;
            a0 = *(const f16x8*)(ap0 + ko);
            a1 = *(const f16x8*)(ap1 + ko);
            b0 = *(const f16x8*)(bp0 + ko);
            b1 = *(const f16x8*)(bp1 + ko);
        }
        f16x8 af[4], bf[4];
#pragma unroll
        for (int i = 0; i < 4; ++i) af[i] = *(const f16x8*)&sA[(wm + i * 16 + fr) * 32 + fk];
#pragma unroll
        for (int i = 0; i < 4; ++i) bf[i] = *(const f16x8*)&sB[(wn + i * 16 + fr) * 32 + fk];
#pragma unroll
        for (int i = 0; i < 4; ++i)
#pragma unroll
            for (int j = 0; j < 4; ++j)
                acc[i][j] = __builtin_amdgcn_mfma_f32_16x16x32_f16(af[i], bf[j], acc[i][j], 0, 0, 0);
    }

    const int orow = (lane >> 4) * 4;  // C/D: col=lane&15, row=(lane>>4)*4+reg
#pragma unroll
    for (int i = 0; i < 4; ++i) {
#pragma unroll
        for (int j = 0; j < 4; ++j) {
            const int gcol = n0 + wn + j * 16 + fr;
            if (gcol < N) {
                const float bb = bias ? bias[gcol] : 0.f;
#pragma unroll
                for (int r = 0; r < 4; ++r) {
                    const int grow = m0 + wm + i * 16 + orow + r;
                    C[(size_t)grow * N + gcol] = (f16)(acc[i][j][r] + bb);
                }
            }
        }
    }
}

// ---------------- LSTM recurrence over one t-chunk; (h,c) state carried in ws ----------------
// R8/R9: one gate row per thread (832 threads, 800 active) -> 25 uint4 = 100 weight VGPRs,
// total pressure ~120 < the 128-VGPR budget the backend pins for this kernel. R6/R7 showed
// 2 rows/thread (200 VGPRs) gets rematerialized from L2 every step (42 GB/dispatch -> 1.13 ms).
#define REP25(M) M(0) M(1) M(2) M(3) M(4) M(5) M(6) M(7) M(8) M(9) M(10) M(11) M(12) \
                 M(13) M(14) M(15) M(16) M(17) M(18) M(19) M(20) M(21) M(22) M(23) M(24)

__global__ __launch_bounds__(832, 4) void rec_kernel(
    const f16* __restrict__ pre,  // [dir][S*BB*H4]
    const uint32_t* __restrict__ whh_f, const uint32_t* __restrict__ whh_b,
    f16* __restrict__ hout, int S, int tf0, int tb0,
    uint32_t* __restrict__ hstate, float* __restrict__ cstate, int first) {
    const int dir = blockIdx.x & 1;
    const int b = blockIdx.x >> 1;
    const f16* __restrict__ prez = pre + (size_t)dir * S * BB * H4;
    const uint32_t* __restrict__ whh = dir ? whh_b : whh_f;
    const int tid = threadIdx.x;

    __shared__ __align__(16) f16 hsh[200];
    __shared__ float gsh[800];

    // one whh row per thread; threads >=800 load row 0 (values unused) to stay non-divergent
    const int row = (tid < 800) ? tid : 0;
    const uint4* wr = (const uint4*)(whh + (size_t)row * 100);
#define WLOAD(n) uint4 w##n = wr[n];
    REP25(WLOAD)
#undef WLOAD

    if (tid < 100) ((uint32_t*)hsh)[tid] = first ? 0u : hstate[(dir * BB + b) * 100 + tid];
    float c = 0.f;
    if (!first && tid < 200) c = cstate[(dir * BB + b) * 200 + tid];
    __syncthreads();

    const int hoff = dir * 200;
    const bool istanh = (tid >= 400 && tid < 600);  // gate g rows
    const f16* pbase = prez + (size_t)b * H4 + row;
    float pv;
    {
        int lt0 = dir ? (S - 1) : 0;
        pv = (float)pbase[(size_t)lt0 * BB * H4];
    }

    for (int step = 0; step < S; ++step) {
        const int lt = dir ? (S - 1 - step) : step;
        const int t = (dir ? tb0 : tf0) + lt;
        float acc0 = pv;
        if (step + 1 < S) {  // prefetch next step's pre (hidden under the dot)
            int ltn = dir ? (S - 2 - step) : (step + 1);
            pv = (float)pbase[(size_t)ltn * BB * H4];
        }
        if (tid < 800) {
            const uint4* hp = (const uint4*)hsh;
#define WDOT(n) { uint4 q = hp[n]; \
            acc0 = fdot2_(w##n.x, q.x, acc0); \
            acc0 = fdot2_(w##n.y, q.y, acc0); \
            acc0 = fdot2_(w##n.z, q.z, acc0); \
            acc0 = fdot2_(w##n.w, q.w, acc0); }
            REP25(WDOT)
#undef WDOT
            gsh[tid] = istanh ? tanh_(acc0) : sigm_(acc0);
        }
        __syncthreads();
        if (tid < 200) {
            float ai = gsh[tid], af = gsh[200 + tid], ag = gsh[400 + tid], ao = gsh[600 + tid];
            c = af * c + ai * ag;
            float h = ao * tanh_(c);
            hsh[tid] = (f16)h;
            hout[((size_t)t * BB + b) * 416 + hoff + tid] = (f16)h;
        } else if (dir == 0 && tid >= 800 && tid < 816) {
            // zero K-pad cols [400,416) (ws poisoned; next GEMM reads Kp=416)
            hout[((size_t)t * BB + b) * 416 + 400 + (tid - 800)] = (f16)0.f;
        }
        __syncthreads();
    }
    // save carry state (hsh final after loop-ending barrier)
    if (tid < 100) hstate[(dir * BB + b) * 100 + tid] = ((const uint32_t*)hsh)[tid];
    if (tid < 200) cstate[(dir * BB + b) * 200 + tid] = c;
}

// ---------------- path gather + tanh + 4-logit + softmax: one wave per output row ----------------
__global__ void final_kernel(const int* __restrict__ paths, const f16* __restrict__ uv,
                             const float* __restrict__ b1, const float* __restrict__ w2,
                             const float* __restrict__ b2, float* __restrict__ out) {
    const int row = blockIdx.x * 4 + (threadIdx.x >> 6);  // b*256 + p, < 32768
    const int lane = threadIdx.x & 63;
    const int b = row >> 8;  // P = 256
    const int t0 = paths[row * 2], t1 = paths[row * 2 + 1];
    const f16* u = (t0 >= 0) ? (uv + ((size_t)t0 * BB + b) * 400) : nullptr;
    const f16* v = (t1 >= 0) ? (uv + ((size_t)t1 * BB + b) * 400 + 200) : nullptr;
    float l0 = 0.f, l1 = 0.f, l2 = 0.f, l3 = 0.f;
    for (int j = lane; j < 200; j += 64) {
        float s = b1[j];
        if (u) s += (float)u[j];
        if (v) s += (float)v[j];
        float hid = tanh_(s);
        l0 += hid * w2[j];
        l1 += hid * w2[200 + j];
        l2 += hid * w2[400 + j];
        l3 += hid * w2[600 + j];
    }
#pragma unroll
    for (int off = 32; off > 0; off >>= 1) {
        l0 += __shfl_down(l0, off);
        l1 += __shfl_down(l1, off);
        l2 += __shfl_down(l2, off);
        l3 += __shfl_down(l3, off);
    }
    if (lane == 0) {
        l0 += b2[0]; l1 += b2[1]; l2 += b2[2]; l3 += b2[3];
        float m = fmaxf(fmaxf(l0, l1), fmaxf(l2, l3));
        float e0 = __expf(l0 - m), e1 = __expf(l1 - m), e2 = __expf(l2 - m), e3 = __expf(l3 - m);
        float inv = 1.f / (e0 + e1 + e2 + e3);
        out[row * 4 + 0] = e0 * inv;
        out[row * 4 + 1] = e1 * inv;
        out[row * 4 + 2] = e2 * inv;
        out[row * 4 + 3] = e3 * inv;
    }
}

extern "C" void kernel_launch(void* const* d_in, const int* in_sizes, int n_in,
                              void* d_out, int out_size, void* d_ws, size_t ws_size,
                              hipStream_t stream) {
    (void)in_sizes; (void)n_in; (void)out_size;
    const int* tokens = (const int*)d_in[0];
    const int* paths = (const int*)d_in[1];
    const float* emb = (const float*)d_in[2];
    const float* wih0f = (const float*)d_in[3];
    const float* whh0f = (const float*)d_in[4];
    const float* bih0f = (const float*)d_in[5];
    const float* bhh0f = (const float*)d_in[6];
    const float* wih0b = (const float*)d_in[7];
    const float* whh0b = (const float*)d_in[8];
    const float* bih0b = (const float*)d_in[9];
    const float* bhh0b = (const float*)d_in[10];
    const float* wih1f = (const float*)d_in[11];
    const float* whh1f = (const float*)d_in[12];
    const float* bih1f = (const float*)d_in[13];
    const float* bhh1f = (const float*)d_in[14];
    const float* wih1b = (const float*)d_in[15];
    const float* whh1b = (const float*)d_in[16];
    const float* bih1b = (const float*)d_in[17];
    const float* bhh1b = (const float*)d_in[18];
    const float* w1 = (const float*)d_in[19];
    const float* b1 = (const float*)d_in[20];
    const float* w2 = (const float*)d_in[21];
    const float* b2 = (const float*)d_in[22];

    uint8_t* ws = (uint8_t*)d_ws;
    size_t off = 0;
    auto carve = [&](size_t bytes) {
        uint8_t* p = ws + off;
        off += (bytes + 255) & ~(size_t)255;
        return p;
    };
    f16* wih0f_h = (f16*)carve(896 * 224 * 2);
    f16* wih0b_h = (f16*)carve(896 * 224 * 2);
    f16* wih1f_h = (f16*)carve(896 * 416 * 2);
    f16* wih1b_h = (f16*)carve(896 * 416 * 2);
    f16* w1r_h = (f16*)carve(512 * 416 * 2);
    uint32_t* whhT = (uint32_t*)carve((size_t)4 * 80000 * 4);
    float* biasd = (float*)carve(4 * 800 * 4);
    uint32_t* hstate = (uint32_t*)carve((size_t)2 * BB * 100 * 4);
    float* cstate = (float*)carve((size_t)2 * BB * 200 * 4);
    f16* xh = (f16*)carve((size_t)65536 * 224 * 2);
    f16* h0h = (f16*)carve((size_t)65536 * 416 * 2);
    f16* h1h = (f16*)carve((size_t)65536 * 416 * 2);
    // pre chunk: largest S (steps/chunk) whose both-direction buffer fits ws_size
    int S = TT;
    while (S > 32 && off + ((size_t)2 * S * BB * H4 * 2 + 256) > ws_size) S >>= 1;
    f16* pre = (f16*)carve((size_t)2 * S * BB * H4 * 2);
    f16* pre_b = pre + (size_t)S * BB * H4;
    f16* uvh = h0h;  // uv (65536x400 f16 = 52.4 MB) aliases h0h (dead after layer-1 GEMM)
    const int nch = TT / S;

    conv_w_kernel<<<784, 256, 0, stream>>>(wih0f, wih0f_h, 800, 200, 896, 224);
    conv_w_kernel<<<784, 256, 0, stream>>>(wih0b, wih0b_h, 800, 200, 896, 224);
    conv_w_kernel<<<1456, 256, 0, stream>>>(wih1f, wih1f_h, 800, 400, 896, 416);
    conv_w_kernel<<<1456, 256, 0, stream>>>(wih1b, wih1b_h, 800, 400, 896, 416);
    conv_w1r_kernel<<<832, 256, 0, stream>>>(w1, w1r_h);
    conv_whh_kernel<<<dim3(313, 4), 256, 0, stream>>>(whh0f, whh0b, whh1f, whh1b, whhT);
    conv_bias_kernel<<<dim3(4, 4), 256, 0, stream>>>(bih0f, bhh0f, bih0b, bhh0b,
                                                     bih1f, bhh1f, bih1b, bhh1b, biasd);
    xgather_kernel<<<65536, 256, 0, stream>>>(tokens, emb, xh);

    // layer 0
    for (int c = 0; c < nch; ++c) {
        const int tf0 = c * S, tb0 = TT - (c + 1) * S;
        gemm_kernel<<<dim3(S, 7, 2), 256, 0, stream>>>(xh, wih0f_h, wih0b_h, biasd, biasd + 800,
                                                       pre, pre_b, 800, 224, 7, tf0 * BB, tb0 * BB);
        rec_kernel<<<256, 832, 0, stream>>>(pre, whhT, whhT + 80000, h0h, S, tf0, tb0,
                                            hstate, cstate, c == 0);
    }
    // layer 1
    for (int c = 0; c < nch; ++c) {
        const int tf0 = c * S, tb0 = TT - (c + 1) * S;
        gemm_kernel<<<dim3(S, 7, 2), 256, 0, stream>>>(h0h, wih1f_h, wih1b_h, biasd + 1600, biasd + 2400,
                                                       pre, pre_b, 800, 416, 13, tf0 * BB, tb0 * BB);
        rec_kernel<<<256, 832, 0, stream>>>(pre, whhT + 160000, whhT + 240000, h1h, S, tf0, tb0,
                                            hstate, cstate, c == 0);
    }
    // MLP precompute uv then fused gather+softmax
    gemm_kernel<<<dim3(512, 4, 1), 256, 0, stream>>>(h1h, w1r_h, nullptr, nullptr, nullptr,
                                                     uvh, nullptr, 400, 416, 13, 0, 0);
    final_kernel<<<8192, 256, 0, stream>>>(paths, uvh, b1, w2, b2, (float*)d_out);
}